// Round 6
// baseline (62.932 us; speedup 1.0000x reference)
//
#include <hip/hip_runtime.h>
#include <hip/hip_bf16.h>
#include <stdint.h>

#define BATCH 8192
#define DIM   1024
#define BM 128
#define BN 128
#define BK 64
#define NT (DIM / BK)   // 16

typedef __attribute__((ext_vector_type(4))) float f32x4;
typedef __attribute__((ext_vector_type(8))) short bf16x8;
typedef __attribute__((ext_vector_type(4))) unsigned short u16x4;
typedef __attribute__((ext_vector_type(8))) unsigned short u16x8;

#define AS1(p) ((const __attribute__((address_space(1))) void*)(p))
#define AS3(p) ((__attribute__((address_space(3))) void*)(p))

__device__ __forceinline__ unsigned short f2bf(float f) {
    union { __hip_bfloat16 h; unsigned short u; } v;
    v.h = __hip_bfloat16(f);
    return v.u;
}

__device__ __forceinline__ float sigma_f(float x) {
    float x2 = x * x;
    return x2 * __builtin_amdgcn_rcpf(1.0f + x2);
}

// ---------------------------------------------------------------------------
// Kernel 1: convert A (f32 [D][D]) to bf16
// ---------------------------------------------------------------------------
__global__ __launch_bounds__(256) void convA_kernel(
    const float* __restrict__ A, unsigned short* __restrict__ Ab)
{
    int idx = blockIdx.x * 256 + threadIdx.x;
    f32x4 av = ((const f32x4*)A)[idx];
    u16x4 ab;
#pragma unroll
    for (int i = 0; i < 4; ++i) ab[i] = f2bf(av[i]);
    ((u16x4*)Ab)[idx] = ab;
}

// ---------------------------------------------------------------------------
// Kernel 2: fused, TWO bn-tiles per block for latency/BW overlap.
//   256 blocks (1/CU), 8 waves (wave grid 2x4: 64x32/wave, acc[4][2]).
//   LDS: [0,64K) staging dbuf {As0,Bs0,As1,Bs1 16K each}; [64K,128K) C-tile.
//   P0: K-loop(bn0) + out2-zero stores interleaved.
//   P1: K-loop(bn1) + epilogue(bn0) passes interleaved (odd iters).
//   P2: epilogue(bn1).
// ---------------------------------------------------------------------------
__global__ __launch_bounds__(512, 2) void fused_kernel(
    const float* __restrict__ x, const float* __restrict__ ex,
    const float* __restrict__ W, const float* __restrict__ tgt,
    const unsigned short* __restrict__ Ab,
    float* __restrict__ out0, float* __restrict__ out1,
    float* __restrict__ out2)
{
    __shared__ __align__(16) char lds[131072];
    char* Cl = lds + 65536;                      // C f32[128][128], swizzled

    // ---- block mapping: same-bm blocks co-locate on one XCD
    const int b     = blockIdx.x;
    const int xcd   = b & 7;
    const int local = b >> 3;                    // 0..31
    const int bm    = xcd * 8 + (local >> 2);    // 0..63
    const int bn0   = (local & 3) * 2;           // 0,2,4,6
    const int bn1   = bn0 + 1;

    const int tid  = threadIdx.x;
    const int lane = tid & 63;
    const int wid  = tid >> 6;                   // 0..7
    const int wr   = wid >> 2;                   // 0..1
    const int wc   = wid & 3;                    // 0..3
    const int l15  = lane & 15;

    // ---- B staging (global_load_lds, pre-swizzled source, linear LDS dest)
    const int swz = (((lane & 7) ^ (lane >> 3)) << 4);
    const char* gBb = (const char*)Ab +
        ((size_t)(wid * 8 + (lane >> 3)) * DIM) * 2 + swz;

    // ---- A(sigma) staging: thread -> rows r0, r0+64; col group g (8 f32)
    const int r0 = tid >> 3;                     // 0..63
    const int g  = tid & 7;
    const float* gx = x + (size_t)(bm * BM + r0) * DIM + g * 8;
    const int wAoff = (g * 16) ^ ((r0 & 7) << 4);

    // ---- fragment read constants
    const int rd_sw = (lane & 7) << 4;
    const int cb0   = (lane >> 4) << 4;

    f32x4 acc[4][2];

    auto stageB = [&](int bn, int k, char* Bs) {
        const char* gB = gBb + (size_t)bn * (BN * DIM * 2) + (size_t)k * 2;
#pragma unroll
        for (int j = 0; j < 2; ++j)
            __builtin_amdgcn_global_load_lds(
                AS1(gB + (size_t)j * (64 * DIM * 2)),
                AS3(Bs + (wid * 8 + j * 64) * 128), 16, 0, 0);
    };
    auto loadX = [&](int k, f32x4 xa[2][2]) {
#pragma unroll
        for (int s = 0; s < 2; ++s) {
            xa[s][0] = *(const f32x4*)(gx + (size_t)s * 64 * DIM + k);
            xa[s][1] = *(const f32x4*)(gx + (size_t)s * 64 * DIM + k + 4);
        }
    };
    auto writeSig = [&](char* As, f32x4 xa[2][2]) {
#pragma unroll
        for (int s = 0; s < 2; ++s) {
            u16x8 sb;
#pragma unroll
            for (int i = 0; i < 4; ++i) {
                sb[i]     = f2bf(sigma_f(xa[s][0][i]));
                sb[i + 4] = f2bf(sigma_f(xa[s][1][i]));
            }
            *(u16x8*)(As + (r0 + s * 64) * 128 + wAoff) = sb;
        }
    };
    auto mfmaPhase = [&](const char* buf) {
        const char* As_ = buf;
        const char* Bs_ = buf + 16384;
#pragma unroll
        for (int kk = 0; kk < 2; ++kk) {
            bf16x8 af[4], bfr[2];
#pragma unroll
            for (int mi = 0; mi < 4; ++mi)
                af[mi] = *(const bf16x8*)(As_ + (wr * 64 + mi * 16 + l15) * 128 +
                                          ((cb0 + kk * 64) ^ rd_sw));
#pragma unroll
            for (int ni = 0; ni < 2; ++ni)
                bfr[ni] = *(const bf16x8*)(Bs_ + (wc * 32 + ni * 16 + l15) * 128 +
                                           ((cb0 + kk * 64) ^ rd_sw));
#pragma unroll
            for (int mi = 0; mi < 4; ++mi)
#pragma unroll
                for (int ni = 0; ni < 2; ++ni)
                    acc[mi][ni] = __builtin_amdgcn_mfma_f32_16x16x32_bf16(
                        af[mi], bfr[ni], acc[mi][ni], 0, 0, 0);
        }
    };
    auto dumpC = [&]() {
#pragma unroll
        for (int mi = 0; mi < 4; ++mi)
#pragma unroll
            for (int ni = 0; ni < 2; ++ni) {
                const int row_ = wr * 64 + mi * 16 + ((lane >> 4) << 2);
                const int colb = (wc * 32 + ni * 16 + l15) * 4;
#pragma unroll
                for (int r = 0; r < 4; ++r) {
                    const int rr = row_ + r;
                    *(float*)(Cl + rr * 512 + (colb ^ (((rr >> 2) & 7) << 4))) = acc[mi][ni][r];
                }
            }
    };

#pragma unroll
    for (int mi = 0; mi < 4; ++mi)
#pragma unroll
        for (int ni = 0; ni < 2; ++ni)
            acc[mi][ni] = f32x4{0.f, 0.f, 0.f, 0.f};

    // ================= P0: K-loop(bn0), zeros for out2 interleaved =========
    {
        f32x4 xa[2][2];
        loadX(0, xa);
        stageB(bn0, 0, lds + 16384);
        writeSig(lds, xa);
    }
    __syncthreads();

    for (int t = 0; t < NT; ++t) {
        const int cur = t & 1;
        f32x4 xa[2][2];
        if (t + 1 < NT) {
            loadX((t + 1) * BK, xa);
            stageB(bn0, (t + 1) * BK, lds + (cur ^ 1) * 32768 + 16384);
        }
        // out2 zeros: 1 f32x4 per thread per iter covers both tiles
        {
            const int j = t * 512 + tid;
            const int tile = j >> 12;            // 0..1
            const int v = j & 4095;
            const size_t v4 = (size_t)(bm * BM + (v >> 5)) * (DIM / 4) +
                              (bn0 + tile) * 32 + (v & 31);
            ((f32x4*)out2)[v4] = f32x4{0.f, 0.f, 0.f, 0.f};
        }
        __builtin_amdgcn_sched_barrier(0);
        mfmaPhase(lds + cur * 32768);
        __builtin_amdgcn_sched_barrier(0);
        if (t + 1 < NT) writeSig(lds + (cur ^ 1) * 32768, xa);
        __syncthreads();
    }

    // ---- dump C(bn0), re-init acc, stage P1 tile 0
    dumpC();
#pragma unroll
    for (int mi = 0; mi < 4; ++mi)
#pragma unroll
        for (int ni = 0; ni < 2; ++ni)
            acc[mi][ni] = f32x4{0.f, 0.f, 0.f, 0.f};
    {
        f32x4 xa[2][2];
        loadX(0, xa);
        stageB(bn1, 0, lds + 16384);
        writeSig(lds, xa);
    }
    __syncthreads();

    // ================= P1: K-loop(bn1) + epilogue(bn0) interleaved =========
    for (int t = 0; t < NT; ++t) {
        const int cur = t & 1;
        f32x4 xa[2][2];
        if (t + 1 < NT) {
            loadX((t + 1) * BK, xa);
            stageB(bn1, (t + 1) * BK, lds + (cur ^ 1) * 32768 + 16384);
        }
        // epilogue(bn0) pass p = t>>1 on odd iters: issue loads EARLY
        f32x4 eC, eX, eE, eW, eT;
        size_t ev4 = 0;
        const bool doEpi = (t & 1);
        if (doEpi) {
            const int p  = t >> 1;
            const int ci = tid + p * 512;
            const int row = ci >> 5;
            const int cv  = ci & 31;
            eC = *(const f32x4*)(Cl + row * 512 + ((cv * 16) ^ (((row >> 2) & 7) << 4)));
            ev4 = (size_t)(bm * BM + row) * (DIM / 4) + bn0 * 32 + cv;
            eX = ((const f32x4*)x)[ev4];
            eE = ((const f32x4*)ex)[ev4];
            eW = ((const f32x4*)W)[ev4];
            eT = ((const f32x4*)tgt)[bn0 * 32 + cv];
        }
        __builtin_amdgcn_sched_barrier(0);
        mfmaPhase(lds + cur * 32768);
        __builtin_amdgcn_sched_barrier(0);
        if (t + 1 < NT) writeSig(lds + (cur ^ 1) * 32768, xa);
        if (doEpi) {
            f32x4 o0;
#pragma unroll
            for (int e = 0; e < 4; ++e) {
                float xi = eX[e], ti = eT[e];
                float ba = ti * ti * __builtin_amdgcn_rcpf(1.0f + ti * ti);
                float u  = -(eW[e] * (xi + eE[e] - ti)) * ba;
                float s  = sigma_f(xi);
                o0[e] = -xi + u * s + eC[e];
            }
            ((f32x4*)out0)[ev4] = o0;
            ((f32x4*)out1)[ev4] = -o0;
        }
        __syncthreads();
    }

    // ---- dump C(bn1)
    dumpC();
    __syncthreads();

    // ================= P2: epilogue(bn1) ====================================
#pragma unroll
    for (int p = 0; p < 8; ++p) {
        const int ci = tid + p * 512;
        const int row = ci >> 5;
        const int cv  = ci & 31;
        f32x4 c = *(const f32x4*)(Cl + row * 512 + ((cv * 16) ^ (((row >> 2) & 7) << 4)));
        const size_t v4 = (size_t)(bm * BM + row) * (DIM / 4) + bn1 * 32 + cv;
        f32x4 xv = ((const f32x4*)x)[v4];
        f32x4 evv = ((const f32x4*)ex)[v4];
        f32x4 wv = ((const f32x4*)W)[v4];
        f32x4 tv = ((const f32x4*)tgt)[bn1 * 32 + cv];
        f32x4 o0;
#pragma unroll
        for (int e = 0; e < 4; ++e) {
            float xi = xv[e], ti = tv[e];
            float ba = ti * ti * __builtin_amdgcn_rcpf(1.0f + ti * ti);
            float u  = -(wv[e] * (xi + evv[e] - ti)) * ba;
            float s  = sigma_f(xi);
            o0[e] = -xi + u * s + c[e];
        }
        ((f32x4*)out0)[v4] = o0;
        ((f32x4*)out1)[v4] = -o0;
    }
}

// ---------------------------------------------------------------------------
extern "C" void kernel_launch(void* const* d_in, const int* in_sizes, int n_in,
                              void* d_out, int out_size, void* d_ws, size_t ws_size,
                              hipStream_t stream)
{
    const float* x   = (const float*)d_in[0];
    const float* ex  = (const float*)d_in[1];
    const float* W   = (const float*)d_in[2];
    const float* A   = (const float*)d_in[3];
    const float* tgt = (const float*)d_in[4];

    float* out0 = (float*)d_out;
    float* out1 = out0 + (size_t)BATCH * DIM;
    float* out2 = out1 + (size_t)BATCH * DIM;

    unsigned short* Abf = (unsigned short*)d_ws;   // 2 MiB

    convA_kernel<<<DIM * DIM / 4 / 256, 256, 0, stream>>>(A, Abf);
    fused_kernel<<<(BATCH / BM) * (DIM / BN) / 2, 512, 0, stream>>>(
        x, ex, W, tgt, Abf, out0, out1, out2);
}